// Round 8
// baseline (402.533 us; speedup 1.0000x reference)
//
#include <hip/hip_runtime.h>
#include <cstdint>
#include <cstddef>

#define NN 20000
#define NE 320000
#define HD 512
#define NG 400
#define NHID ((size_t)NN * HD)
#define FCK 3072   // padded 3020
#define FCN 256

typedef __attribute__((ext_vector_type(4))) float f32x4;
typedef __attribute__((ext_vector_type(2))) float f32x2;
typedef __attribute__((ext_vector_type(8))) short s16x8;
typedef __attribute__((ext_vector_type(4))) short s16x4;
typedef __attribute__((ext_vector_type(2))) unsigned int u32x2;

#if defined(__has_builtin)
#if __has_builtin(__builtin_amdgcn_cvt_pk_f32_fp8)
#define HAS_HW_FP8 1
#endif
#endif

__device__ __forceinline__ unsigned short f2bf(float f) {
  uint32_t u = __builtin_bit_cast(uint32_t, f);
  uint32_t r = u + 0x7fffu + ((u >> 16) & 1u);
  return (unsigned short)(r >> 16);
}
__device__ __forceinline__ float bf2f(unsigned short h) {
  return __builtin_bit_cast(float, (uint32_t)h << 16);
}

// ---- fp8 e4m3fn encode (SW, emits only normal patterns: denorm->0, clamp<=448) ----
__device__ __forceinline__ uint32_t f32_to_fp8(float f) {
  float af = fabsf(f);
  af = fminf(af, 440.f);
  uint32_t u = __builtin_bit_cast(uint32_t, af);
  u += 0x7ffffu + ((u >> 20) & 1u);
  uint32_t e = u >> 23;
  uint32_t out = (e < 121u) ? 0u : (((e - 120u) << 3) | ((u >> 20) & 7u));
  return out | ((__builtin_bit_cast(uint32_t, f) >> 24) & 0x80u);
}
__device__ __forceinline__ float fp8_to_f32_sw(uint32_t b) {
  uint32_t e = (b >> 3) & 0xfu;
  uint32_t u = ((b & 0x80u) << 24) | ((e + 120u) << 23) | ((b & 7u) << 20);
  return e ? __builtin_bit_cast(float, u) : 0.f;
}
__device__ __forceinline__ void dec8(u32x2 v, float* f) {
#ifdef HAS_HW_FP8
  f32x2 p0 = __builtin_amdgcn_cvt_pk_f32_fp8(v[0], false);
  f32x2 p1 = __builtin_amdgcn_cvt_pk_f32_fp8(v[0], true);
  f32x2 p2 = __builtin_amdgcn_cvt_pk_f32_fp8(v[1], false);
  f32x2 p3 = __builtin_amdgcn_cvt_pk_f32_fp8(v[1], true);
  f[0] = p0[0]; f[1] = p0[1]; f[2] = p1[0]; f[3] = p1[1];
  f[4] = p2[0]; f[5] = p2[1]; f[6] = p3[0]; f[7] = p3[1];
#else
  #pragma unroll
  for (int k = 0; k < 4; ++k) f[k] = fp8_to_f32_sw((v[0] >> (8 * k)) & 0xffu);
  #pragma unroll
  for (int k = 0; k < 4; ++k) f[4 + k] = fp8_to_f32_sw((v[1] >> (8 * k)) & 0xffu);
#endif
}

// ---------------- cast x (f32 -> fp8), 4 elems/thread ----------------
__global__ void cast_x_kernel(const float* __restrict__ in, unsigned char* __restrict__ outp) {
  size_t i = ((size_t)blockIdx.x * 256 + threadIdx.x) * 4;
  f32x4 v = *(const f32x4*)(in + i);
  uint32_t o = 0;
  #pragma unroll
  for (int j = 0; j < 4; ++j) o |= f32_to_fp8(v[j]) << (8 * j);
  *(uint32_t*)(outp + i) = o;
}

// ---------------- merged w1/w2 transpose+cast ----------------
__global__ __launch_bounds__(256) void transpose_w12_kernel(
    const float* __restrict__ w1, const float* __restrict__ w2,
    unsigned short* __restrict__ w1t, unsigned short* __restrict__ w2t) {
  __shared__ float tl[64][65];
  int z = blockIdx.z;
  const float* ip = (z < 3 ? w1 + (size_t)z * 262144 : w2 + (size_t)(z - 3) * 262144);
  unsigned short* op = (z < 3 ? w1t + (size_t)z * 262144 : w2t + (size_t)(z - 3) * 262144);
  int k0 = blockIdx.x * 64;
  int j0 = blockIdx.y * 64;
  int t = threadIdx.x;
  int c = t & 63, r4 = t >> 6;
  #pragma unroll
  for (int rr = 0; rr < 16; ++rr) {
    int r = rr * 4 + r4;
    tl[r][c] = ip[(size_t)(k0 + r) * 512 + j0 + c];
  }
  __syncthreads();
  #pragma unroll
  for (int jj = 0; jj < 16; ++jj) {
    int j = jj * 4 + r4;
    op[(size_t)(j0 + j) * 512 + k0 + c] = f2bf(tl[c][j]);
  }
}

// ---------------- fc1 transpose+cast (3020x256 -> 256x3072 padded) ----------------
__global__ __launch_bounds__(256) void transpose_fc1_kernel(
    const float* __restrict__ in, unsigned short* __restrict__ outp) {
  __shared__ float tl[64][65];
  int k0 = blockIdx.x * 64;
  int j0 = blockIdx.y * 64;
  int t = threadIdx.x;
  int c = t & 63, r4 = t >> 6;
  #pragma unroll
  for (int rr = 0; rr < 16; ++rr) {
    int r = rr * 4 + r4;
    int k = k0 + r;
    tl[r][c] = (k < 3020) ? in[(size_t)k * FCN + j0 + c] : 0.f;
  }
  __syncthreads();
  #pragma unroll
  for (int jj = 0; jj < 16; ++jj) {
    int j = jj * 4 + r4;
    outp[(size_t)(j0 + j) * FCK + k0 + c] = f2bf(tl[c][j]);
  }
}

// ---------------- CSR build: histogram, scan, fill ----------------
__global__ void hist_kernel(const int* __restrict__ ei, int* __restrict__ deg) {
  int e = blockIdx.x * 256 + threadIdx.x;
  if (e >= NE) return;
  atomicAdd(&deg[ei[NE + e]], 1);
}

__global__ __launch_bounds__(1024) void scan_kernel(const int* __restrict__ deg,
                                                    int* __restrict__ rowptr,
                                                    int* __restrict__ cursor) {
  __shared__ int s[1024];
  int t = threadIdx.x;
  int base = t * 20;
  int local[20];
  int sum = 0;
  #pragma unroll
  for (int i = 0; i < 20; ++i) {
    int idx = base + i;
    int d = idx < NN ? deg[idx] : 0;
    local[i] = sum;
    sum += d;
  }
  s[t] = sum;
  __syncthreads();
  for (int off = 1; off < 1024; off <<= 1) {
    int v = (t >= off) ? s[t - off] : 0;
    __syncthreads();
    s[t] += v;
    __syncthreads();
  }
  int pre = (t > 0) ? s[t - 1] : 0;
  #pragma unroll
  for (int i = 0; i < 20; ++i) {
    int idx = base + i;
    if (idx < NN) {
      rowptr[idx] = pre + local[i];
      cursor[idx] = pre + local[i];
    }
  }
  if (t == 1023) rowptr[NN] = s[1023];
}

__global__ void fill_kernel(const int* __restrict__ ei, int* __restrict__ cursor,
                            int* __restrict__ col) {
  int e = blockIdx.x * 256 + threadIdx.x;
  if (e >= NE) return;
  int src = ei[e];
  int dst = ei[NE + e];
  int p = atomicAdd(&cursor[dst], 1);
  col[p] = src;
}

// ---------------- gather-sum over fp8 table (HW cvt decode): hs[n] = bf16(sum) ----
__global__ __launch_bounds__(256) void gather_kernel(
    const unsigned char* __restrict__ h8, const int* __restrict__ rowptr,
    const int* __restrict__ col, unsigned short* __restrict__ hs) {
  int n = blockIdx.x * 4 + (threadIdx.x >> 6);
  int lane = threadIdx.x & 63;
  if (n >= NN) return;
  int lo = rowptr[n], hi = rowptr[n + 1];
  const unsigned char* hl = h8 + (size_t)(lane << 3);
  u32x2 sv = *(const u32x2*)(hl + (size_t)n * 512);
  float a0[8], a1[8], tmp[8];
  dec8(sv, a0);
  #pragma unroll
  for (int i = 0; i < 8; ++i) a1[i] = 0.f;
  int j = lo;
  for (; j + 4 <= hi; j += 4) {
    int c0 = col[j], c1 = col[j + 1], c2 = col[j + 2], c3 = col[j + 3];
    u32x2 v0 = *(const u32x2*)(hl + (size_t)c0 * 512);
    u32x2 v1 = *(const u32x2*)(hl + (size_t)c1 * 512);
    u32x2 v2 = *(const u32x2*)(hl + (size_t)c2 * 512);
    u32x2 v3 = *(const u32x2*)(hl + (size_t)c3 * 512);
    dec8(v0, tmp);
    #pragma unroll
    for (int i = 0; i < 8; ++i) a0[i] += tmp[i];
    dec8(v1, tmp);
    #pragma unroll
    for (int i = 0; i < 8; ++i) a1[i] += tmp[i];
    dec8(v2, tmp);
    #pragma unroll
    for (int i = 0; i < 8; ++i) a0[i] += tmp[i];
    dec8(v3, tmp);
    #pragma unroll
    for (int i = 0; i < 8; ++i) a1[i] += tmp[i];
  }
  for (; j < hi; ++j) {
    u32x2 v0 = *(const u32x2*)(hl + (size_t)col[j] * 512);
    dec8(v0, tmp);
    #pragma unroll
    for (int i = 0; i < 8; ++i) a0[i] += tmp[i];
  }
  s16x8 o;
  #pragma unroll
  for (int i = 0; i < 8; ++i) o[i] = (short)f2bf(a0[i] + a1[i]);
  *(s16x8*)(hs + (size_t)n * HD + (lane << 3)) = o;
}

// ---- stage one 128x64 A-tile + 128x64 B-tile into LDS at bufbase (8 x 16B/thread) ----
#define STAGE_TILE(kkv, bufbase)                                                          \
  do {                                                                                    \
    int kk_ = (kkv);                                                                      \
    unsigned bb_ = (bufbase);                                                             \
    _Pragma("unroll")                                                                     \
    for (int i = 0; i < 4; ++i) {                                                         \
      int ra = i * 32 + row_s;                                                            \
      int rga = m0 + ra; rga = rga < M ? rga : M - 1;                                     \
      const unsigned short* ga = A + (size_t)rga * HD + (kk_ + ((slot_s ^ (ra & 7)) << 3)); \
      __builtin_amdgcn_global_load_lds(                                                   \
          (const __attribute__((address_space(1))) unsigned int*)(const void*)ga,         \
          (__attribute__((address_space(3))) unsigned int*)(void*)(ldsb + bb_ + (unsigned)(i * 4096) + ldso_w), \
          16, 0, 0);                                                                      \
    }                                                                                     \
    _Pragma("unroll")                                                                     \
    for (int i = 0; i < 4; ++i) {                                                         \
      int rb = i * 32 + row_s;                                                            \
      const unsigned short* gb = Bt + (size_t)(n0 + rb) * HD + (kk_ + ((slot_s ^ (rb & 7)) << 3)); \
      __builtin_amdgcn_global_load_lds(                                                   \
          (const __attribute__((address_space(1))) unsigned int*)(const void*)gb,         \
          (__attribute__((address_space(3))) unsigned int*)(void*)(ldsb + bb_ + 16384u + (unsigned)(i * 4096) + ldso_w), \
          16, 0, 0);                                                                      \
    }                                                                                     \
  } while (0)

// ---------------- GEMM (M x 512) @ (512 x 512), XCD swizzle, 2-phase dbuf ----------
// K-loop: [stage(next tile, alt buf)] [compute(cur buf)] [syncthreads = vmcnt drain]
// -> staging latency hides under the 32-MFMA compute phase (T3 minimum-2-phase).
// EPI 1: +bias, prelu, BN affine -> bf16.  EPI 2: +bias, prelu, relu -> bf16.
// EPI 4: +bias, prelu, relu -> fp8 (inter-layer h table).
template <int EPI>
__global__ __launch_bounds__(256, 2) void gemm_bf16(
    const unsigned short* __restrict__ A, const unsigned short* __restrict__ Bt,
    const float* __restrict__ bias, const float* __restrict__ slope,
    const float* __restrict__ bnm, const float* __restrict__ bnv,
    const float* __restrict__ bng, const float* __restrict__ bnb,
    void* __restrict__ Cout, int M) {
  __shared__ unsigned short lds[32768];   // 2 x (A 16KB + B 16KB) = 64KB
  char* ldsb = (char*)lds;
  const int tid = threadIdx.x;
  const int lane = tid & 63;
  const int wid = tid >> 6;
  const int wm = wid >> 1, wn = wid & 1;

  const unsigned bid = blockIdx.x;
  const unsigned nwg = gridDim.x;
  const unsigned q = nwg >> 3, r = nwg & 7;
  const unsigned xcd = bid & 7, idx = bid >> 3;
  const unsigned wgid = (xcd < r ? xcd * (q + 1) : r * (q + 1) + (xcd - r) * q) + idx;
  const int m0 = (int)(wgid >> 2) * 128;
  const int n0 = (int)(wgid & 3) * 128;

  f32x4 acc[4][4];
  #pragma unroll
  for (int m = 0; m < 4; ++m)
    #pragma unroll
    for (int n = 0; n < 4; ++n) acc[m][n] = (f32x4){0.f, 0.f, 0.f, 0.f};

  const int row_s = tid >> 3;
  const int slot_s = tid & 7;
  const unsigned ldso_w = (unsigned)(wid << 10);

  const unsigned swz = (unsigned)((lane & 7) << 4);
  const unsigned koff = (unsigned)((lane >> 4) << 4);
  const unsigned arow = (unsigned)((wm * 64 + (lane & 15)) * 128);
  const unsigned brow = 16384u + (unsigned)((wn * 64 + (lane & 15)) * 128);

  STAGE_TILE(0, 0u);
  __syncthreads();

  unsigned cur = 0;
  for (int kt = 0; kt < 8; ++kt) {
    if (kt < 7) STAGE_TILE((kt + 1) * 64, (cur ^ 1u) * 32768u);
    const unsigned base = cur * 32768u;
    #pragma unroll
    for (int s = 0; s < 2; ++s) {
      s16x8 af[4], bfr[4];
      #pragma unroll
      for (int m = 0; m < 4; ++m)
        af[m] = *(const s16x8*)(ldsb + base + ((arow + (unsigned)(m * 2048 + s * 64) + koff) ^ swz));
      #pragma unroll
      for (int n = 0; n < 4; ++n)
        bfr[n] = *(const s16x8*)(ldsb + base + ((brow + (unsigned)(n * 2048 + s * 64) + koff) ^ swz));
      #pragma unroll
      for (int m = 0; m < 4; ++m)
        #pragma unroll
        for (int n = 0; n < 4; ++n)
          acc[m][n] = __builtin_amdgcn_mfma_f32_16x16x32_bf16(af[m], bfr[n], acc[m][n], 0, 0, 0);
    }
    __syncthreads();   // vmcnt(0)+lgkmcnt(0) drain AFTER compute: prefetch has landed
    cur ^= 1u;
  }

  const float al = slope[0];
  const int colb = n0 + wn * 64 + (lane & 15);
  const int rowb = m0 + wm * 64 + ((lane >> 4) << 2);
  #pragma unroll
  for (int n = 0; n < 4; ++n) {
    const int j = colb + n * 16;
    const float bi = bias[j];
    float sc = 1.f, sh = 0.f;
    if (EPI == 1) {
      sc = bng[j] * (1.f / sqrtf(bnv[j] + 1e-5f));
      sh = bnb[j] - bnm[j] * sc;
    }
    #pragma unroll
    for (int m = 0; m < 4; ++m) {
      #pragma unroll
      for (int r2 = 0; r2 < 4; ++r2) {
        int row = rowb + m * 16 + r2;
        if (row < M) {
          float v = acc[m][n][r2] + bi;
          v = v >= 0.f ? v : al * v;
          if (EPI == 1) v = v * sc + sh;
          else v = fmaxf(v, 0.f);
          if (EPI == 4)
            ((unsigned char*)Cout)[(size_t)row * HD + j] = (unsigned char)f32_to_fp8(v);
          else
            ((unsigned short*)Cout)[(size_t)row * HD + j] = f2bf(v);
        }
      }
    }
  }
}

// ---------------- FC1 GEMM: (400 x 3072) @ (3072 x 256), K-split, fp32 partials ----
__global__ __launch_bounds__(256, 2) void fc_gemm_kernel(
    const unsigned short* __restrict__ A, const unsigned short* __restrict__ Bt,
    float* __restrict__ part) {
  __shared__ unsigned short lds[16384];
  char* ldsb = (char*)lds;
  const int tid = threadIdx.x;
  const int lane = tid & 63;
  const int wid = tid >> 6;
  const int wm = wid >> 1, wn = wid & 1;
  const int m0 = blockIdx.x * 128;
  const int n0 = blockIdx.y * 128;
  const int kbase = blockIdx.z * 512;

  f32x4 acc[4][4];
  #pragma unroll
  for (int m = 0; m < 4; ++m)
    #pragma unroll
    for (int n = 0; n < 4; ++n) acc[m][n] = (f32x4){0.f, 0.f, 0.f, 0.f};

  const int row_s = tid >> 3;
  const int slot_s = tid & 7;
  const unsigned ldso_w = (unsigned)(wid << 10);

  for (int kk = kbase; kk < kbase + 512; kk += 64) {
    __syncthreads();
    #pragma unroll
    for (int i = 0; i < 4; ++i) {
      int ra = i * 32 + row_s;
      int rga = m0 + ra; rga = rga < NG ? rga : NG - 1;
      const unsigned short* ga = A + (size_t)rga * FCK + (kk + ((slot_s ^ (ra & 7)) << 3));
      __builtin_amdgcn_global_load_lds(
          (const __attribute__((address_space(1))) unsigned int*)(const void*)ga,
          (__attribute__((address_space(3))) unsigned int*)(void*)(ldsb + (unsigned)(i * 4096) + ldso_w),
          16, 0, 0);
    }
    #pragma unroll
    for (int i = 0; i < 4; ++i) {
      int rb = i * 32 + row_s;
      const unsigned short* gb = Bt + (size_t)(n0 + rb) * FCK + (kk + ((slot_s ^ (rb & 7)) << 3));
      __builtin_amdgcn_global_load_lds(
          (const __attribute__((address_space(1))) unsigned int*)(const void*)gb,
          (__attribute__((address_space(3))) unsigned int*)(void*)(ldsb + 16384u + (unsigned)(i * 4096) + ldso_w),
          16, 0, 0);
    }
    __syncthreads();

    const unsigned swz = (unsigned)((lane & 7) << 4);
    const unsigned koff = (unsigned)((lane >> 4) << 4);
    const unsigned arow = (unsigned)((wm * 64 + (lane & 15)) * 128);
    const unsigned brow = 16384u + (unsigned)((wn * 64 + (lane & 15)) * 128);
    #pragma unroll
    for (int s = 0; s < 2; ++s) {
      s16x8 af[4], bfr[4];
      #pragma unroll
      for (int m = 0; m < 4; ++m)
        af[m] = *(const s16x8*)(ldsb + ((arow + (unsigned)(m * 2048 + s * 64) + koff) ^ swz));
      #pragma unroll
      for (int n = 0; n < 4; ++n)
        bfr[n] = *(const s16x8*)(ldsb + ((brow + (unsigned)(n * 2048 + s * 64) + koff) ^ swz));
      #pragma unroll
      for (int m = 0; m < 4; ++m)
        #pragma unroll
        for (int n = 0; n < 4; ++n)
          acc[m][n] = __builtin_amdgcn_mfma_f32_16x16x32_bf16(af[m], bfr[n], acc[m][n], 0, 0, 0);
    }
  }

  float* po = part + (size_t)blockIdx.z * (NG * FCN);
  const int colb = n0 + wn * 64 + (lane & 15);
  const int rowb = m0 + wm * 64 + ((lane >> 4) << 2);
  #pragma unroll
  for (int n = 0; n < 4; ++n) {
    const int j = colb + n * 16;
    #pragma unroll
    for (int m = 0; m < 4; ++m) {
      #pragma unroll
      for (int r = 0; r < 4; ++r) {
        int row = rowb + m * 16 + r;
        if (row < NG) po[(size_t)row * FCN + j] = acc[m][n][r];
      }
    }
  }
}

// ---------------- pooling + x_cat build (bf16, padded to 3072) ----------------
__device__ __forceinline__ int lbound(const int* __restrict__ a, int n, int v) {
  int lo = 0, hi = n;
  while (lo < hi) { int m = (lo + hi) >> 1; if (a[m] < v) lo = m + 1; else hi = m; }
  return lo;
}

__global__ __launch_bounds__(256) void pool_xcat_kernel(
    const unsigned short* __restrict__ hs, const int* __restrict__ batch,
    const float* __restrict__ stats, const float* __restrict__ adj,
    unsigned short* __restrict__ xcat) {
  int g = blockIdx.x, t = threadIdx.x;
  int lo = lbound(batch, NN, g);
  int hi = lbound(batch, NN, g + 1);
  float s0 = 0.f, s1 = 0.f;
  for (int n = lo; n < hi; ++n) {
    uint32_t v = *(const uint32_t*)(hs + (size_t)n * HD + 2 * t);
    s0 += bf2f((unsigned short)(v & 0xffffu));
    s1 += bf2f((unsigned short)(v >> 16));
  }
  unsigned short* row = xcat + (size_t)g * FCK;
  row[2 * t] = f2bf(s0);
  row[2 * t + 1] = f2bf(s1);
  if (t < 8) row[HD + t] = f2bf(stats[g * 8 + t]);
  for (int i = t; i < 2500; i += 256) row[520 + i] = f2bf(adj[(size_t)g * 2500 + i]);
  if (t < 52) row[3020 + t] = 0;
}

// ---------------- FC epilogue: bias+relu -> x_l, fc2 dot -> sigmoid ----------------
__global__ __launch_bounds__(256) void fc_epi_kernel(
    const float* __restrict__ part, const float* __restrict__ b1,
    const float* __restrict__ w2, const float* __restrict__ b2,
    float* __restrict__ outp) {
  __shared__ float red[256];
  int g = blockIdx.x, t = threadIdx.x;
  float s = b1[t];
  #pragma unroll
  for (int ks = 0; ks < 6; ++ks) s += part[(size_t)ks * (NG * FCN) + g * FCN + t];
  float xl = fmaxf(s, 0.f);
  outp[NG + g * FCN + t] = xl;
  red[t] = xl * w2[t];
  __syncthreads();
  for (int st = 128; st > 0; st >>= 1) {
    if (t < st) red[t] += red[t + st];
    __syncthreads();
  }
  if (t == 0) outp[g] = 1.f / (1.f + expf(-(red[0] + b2[0])));
}

extern "C" void kernel_launch(void* const* d_in, const int* in_sizes, int n_in,
                              void* d_out, int out_size, void* d_ws, size_t ws_size,
                              hipStream_t stream) {
  const float* x = (const float*)d_in[0];
  const int* ei = (const int*)d_in[1];
  const int* batch = (const int*)d_in[2];
  const float* stats = (const float*)d_in[3];
  const float* adj = (const float*)d_in[4];
  const float* w1 = (const float*)d_in[5];
  const float* b1 = (const float*)d_in[6];
  const float* a1 = (const float*)d_in[7];
  const float* bng = (const float*)d_in[8];
  const float* bnb = (const float*)d_in[9];
  const float* bnm = (const float*)d_in[10];
  const float* bnv = (const float*)d_in[11];
  const float* w2 = (const float*)d_in[12];
  const float* b2 = (const float*)d_in[13];
  const float* a2 = (const float*)d_in[14];
  const float* fc1w = (const float*)d_in[15];
  const float* fc1b = (const float*)d_in[16];
  const float* fc2w = (const float*)d_in[17];
  const float* fc2b = (const float*)d_in[18];
  float* outp = (float*)d_out;

  char* ws = (char*)d_ws;
  unsigned char* h8 = (unsigned char*)ws;     ws += NHID;              // fp8 inter-layer h
  unsigned short* hsb = (unsigned short*)ws;  ws += NHID * 2;          // bf16 h+agg / final h
  unsigned short* h1b = (unsigned short*)ws;  ws += NHID * 2;          // bf16 mid
  unsigned short* w1t = (unsigned short*)ws;  ws += (size_t)3 * 512 * 512 * 2;
  unsigned short* w2t = (unsigned short*)ws;  ws += (size_t)3 * 512 * 512 * 2;
  int* deg = (int*)ws;                        ws += (size_t)NN * 4;
  int* rowptr = (int*)ws;                     ws += (size_t)(NN + 4) * 4;
  int* cursor = (int*)ws;                     ws += (size_t)NN * 4;
  int* col = (int*)ws;                        ws += (size_t)NE * 4;
  unsigned short* xcat = (unsigned short*)ws; ws += (size_t)NG * FCK * 2;
  unsigned short* fc1t = (unsigned short*)ws; ws += (size_t)FCN * FCK * 2;
  float* fcpart = (float*)ws;                 ws += (size_t)6 * NG * FCN * 4;

  // CSR build
  hipMemsetAsync(deg, 0, (size_t)NN * 4, stream);
  hist_kernel<<<(NE + 255) / 256, 256, 0, stream>>>(ei, deg);
  scan_kernel<<<1, 1024, 0, stream>>>(deg, rowptr, cursor);
  fill_kernel<<<(NE + 255) / 256, 256, 0, stream>>>(ei, cursor, col);

  cast_x_kernel<<<(int)(NHID / 1024), 256, 0, stream>>>(x, h8);
  transpose_w12_kernel<<<dim3(8, 8, 6), 256, 0, stream>>>(w1, w2, w1t, w2t);
  transpose_fc1_kernel<<<dim3(FCK / 64, FCN / 64, 1), 256, 0, stream>>>(fc1w, fc1t);

  for (int l = 0; l < 3; ++l) {
    gather_kernel<<<NN / 4, 256, 0, stream>>>(h8, rowptr, col, hsb);
    gemm_bf16<1><<<628, 256, 0, stream>>>(hsb, w1t + (size_t)l * 262144,
        b1 + l * 512, a1 + l, bnm + l * 512, bnv + l * 512, bng + l * 512, bnb + l * 512,
        (void*)h1b, NN);
    if (l < 2) {
      gemm_bf16<4><<<628, 256, 0, stream>>>(h1b, w2t + (size_t)l * 262144,
          b2 + l * 512, a2 + l, nullptr, nullptr, nullptr, nullptr, (void*)h8, NN);
    } else {
      gemm_bf16<2><<<628, 256, 0, stream>>>(h1b, w2t + (size_t)l * 262144,
          b2 + l * 512, a2 + l, nullptr, nullptr, nullptr, nullptr, (void*)hsb, NN);
    }
  }

  pool_xcat_kernel<<<NG, 256, 0, stream>>>(hsb, batch, stats, adj, xcat);
  fc_gemm_kernel<<<dim3(4, 2, 6), 256, 0, stream>>>(xcat, fc1t, fcpart);
  fc_epi_kernel<<<NG, 256, 0, stream>>>(fcpart, fc1b, fc2w, fc2b, outp);
}

// Round 10
// 324.296 us; speedup vs baseline: 1.2413x; 1.2413x over previous
//
#include <hip/hip_runtime.h>
#include <cstdint>
#include <cstddef>

#define NN 20000
#define NE 320000
#define HD 512
#define NG 400
#define NHID ((size_t)NN * HD)
#define FCK 3072   // padded 3020
#define FCN 256

typedef __attribute__((ext_vector_type(4))) float f32x4;
typedef __attribute__((ext_vector_type(2))) float f32x2;
typedef __attribute__((ext_vector_type(8))) short s16x8;
typedef __attribute__((ext_vector_type(4))) short s16x4;
typedef __attribute__((ext_vector_type(2))) unsigned int u32x2;

#if defined(__has_builtin)
#if __has_builtin(__builtin_amdgcn_cvt_pk_f32_fp8)
#define HAS_HW_FP8 1
#endif
#endif

__device__ __forceinline__ unsigned short f2bf(float f) {
  uint32_t u = __builtin_bit_cast(uint32_t, f);
  uint32_t r = u + 0x7fffu + ((u >> 16) & 1u);
  return (unsigned short)(r >> 16);
}
__device__ __forceinline__ float bf2f(unsigned short h) {
  return __builtin_bit_cast(float, (uint32_t)h << 16);
}

// ---- fp8 e4m3fn encode (SW, normals only: denorm->0, clamp<=448); decode HW ----
__device__ __forceinline__ uint32_t f32_to_fp8(float f) {
  float af = fabsf(f);
  af = fminf(af, 440.f);
  uint32_t u = __builtin_bit_cast(uint32_t, af);
  u += 0x7ffffu + ((u >> 20) & 1u);
  uint32_t e = u >> 23;
  uint32_t out = (e < 121u) ? 0u : (((e - 120u) << 3) | ((u >> 20) & 7u));
  return out | ((__builtin_bit_cast(uint32_t, f) >> 24) & 0x80u);
}
__device__ __forceinline__ float fp8_to_f32_sw(uint32_t b) {
  uint32_t e = (b >> 3) & 0xfu;
  uint32_t u = ((b & 0x80u) << 24) | ((e + 120u) << 23) | ((b & 7u) << 20);
  return e ? __builtin_bit_cast(float, u) : 0.f;
}
__device__ __forceinline__ void dec8(u32x2 v, float* f) {
#ifdef HAS_HW_FP8
  f32x2 p0 = __builtin_amdgcn_cvt_pk_f32_fp8(v[0], false);
  f32x2 p1 = __builtin_amdgcn_cvt_pk_f32_fp8(v[0], true);
  f32x2 p2 = __builtin_amdgcn_cvt_pk_f32_fp8(v[1], false);
  f32x2 p3 = __builtin_amdgcn_cvt_pk_f32_fp8(v[1], true);
  f[0] = p0[0]; f[1] = p0[1]; f[2] = p1[0]; f[3] = p1[1];
  f[4] = p2[0]; f[5] = p2[1]; f[6] = p3[0]; f[7] = p3[1];
#else
  #pragma unroll
  for (int k = 0; k < 4; ++k) f[k] = fp8_to_f32_sw((v[0] >> (8 * k)) & 0xffu);
  #pragma unroll
  for (int k = 0; k < 4; ++k) f[4 + k] = fp8_to_f32_sw((v[1] >> (8 * k)) & 0xffu);
#endif
}

// ---------------- cast x (f32 -> fp8), 4 elems/thread ----------------
__global__ void cast_x_kernel(const float* __restrict__ in, unsigned char* __restrict__ outp) {
  size_t i = ((size_t)blockIdx.x * 256 + threadIdx.x) * 4;
  f32x4 v = *(const f32x4*)(in + i);
  uint32_t o = 0;
  #pragma unroll
  for (int j = 0; j < 4; ++j) o |= f32_to_fp8(v[j]) << (8 * j);
  *(uint32_t*)(outp + i) = o;
}

// ---------------- merged w1/w2 transpose+cast (bf16) ----------------
__global__ __launch_bounds__(256) void transpose_w12_kernel(
    const float* __restrict__ w1, const float* __restrict__ w2,
    unsigned short* __restrict__ w1t, unsigned short* __restrict__ w2t) {
  __shared__ float tl[64][65];
  int z = blockIdx.z;
  const float* ip = (z < 3 ? w1 + (size_t)z * 262144 : w2 + (size_t)(z - 3) * 262144);
  unsigned short* op = (z < 3 ? w1t + (size_t)z * 262144 : w2t + (size_t)(z - 3) * 262144);
  int k0 = blockIdx.x * 64;
  int j0 = blockIdx.y * 64;
  int t = threadIdx.x;
  int c = t & 63, r4 = t >> 6;
  #pragma unroll
  for (int rr = 0; rr < 16; ++rr) {
    int r = rr * 4 + r4;
    tl[r][c] = ip[(size_t)(k0 + r) * 512 + j0 + c];
  }
  __syncthreads();
  #pragma unroll
  for (int jj = 0; jj < 16; ++jj) {
    int j = jj * 4 + r4;
    op[(size_t)(j0 + j) * 512 + k0 + c] = f2bf(tl[c][j]);
  }
}

// ---------------- fc1 transpose+cast (3020x256 -> 256x3072 padded) ----------------
__global__ __launch_bounds__(256) void transpose_fc1_kernel(
    const float* __restrict__ in, unsigned short* __restrict__ outp) {
  __shared__ float tl[64][65];
  int k0 = blockIdx.x * 64;
  int j0 = blockIdx.y * 64;
  int t = threadIdx.x;
  int c = t & 63, r4 = t >> 6;
  #pragma unroll
  for (int rr = 0; rr < 16; ++rr) {
    int r = rr * 4 + r4;
    int k = k0 + r;
    tl[r][c] = (k < 3020) ? in[(size_t)k * FCN + j0 + c] : 0.f;
  }
  __syncthreads();
  #pragma unroll
  for (int jj = 0; jj < 16; ++jj) {
    int j = jj * 4 + r4;
    outp[(size_t)(j0 + j) * FCK + k0 + c] = f2bf(tl[c][j]);
  }
}

// ---------------- CSR build: histogram, scan, fill ----------------
__global__ void hist_kernel(const int* __restrict__ ei, int* __restrict__ deg) {
  int e = blockIdx.x * 256 + threadIdx.x;
  if (e >= NE) return;
  atomicAdd(&deg[ei[NE + e]], 1);
}

__global__ __launch_bounds__(1024) void scan_kernel(const int* __restrict__ deg,
                                                    int* __restrict__ rowptr,
                                                    int* __restrict__ cursor) {
  __shared__ int s[1024];
  int t = threadIdx.x;
  int base = t * 20;
  int local[20];
  int sum = 0;
  #pragma unroll
  for (int i = 0; i < 20; ++i) {
    int idx = base + i;
    int d = idx < NN ? deg[idx] : 0;
    local[i] = sum;
    sum += d;
  }
  s[t] = sum;
  __syncthreads();
  for (int off = 1; off < 1024; off <<= 1) {
    int v = (t >= off) ? s[t - off] : 0;
    __syncthreads();
    s[t] += v;
    __syncthreads();
  }
  int pre = (t > 0) ? s[t - 1] : 0;
  #pragma unroll
  for (int i = 0; i < 20; ++i) {
    int idx = base + i;
    if (idx < NN) {
      rowptr[idx] = pre + local[i];
      cursor[idx] = pre + local[i];
    }
  }
  if (t == 1023) rowptr[NN] = s[1023];
}

__global__ void fill_kernel(const int* __restrict__ ei, int* __restrict__ cursor,
                            int* __restrict__ col) {
  int e = blockIdx.x * 256 + threadIdx.x;
  if (e >= NE) return;
  int src = ei[e];
  int dst = ei[NE + e];
  int p = atomicAdd(&cursor[dst], 1);
  col[p] = src;
}

// ------- gather-sum over fp8 table (HW cvt decode): hs[n] = bf16(sum) -------
__global__ __launch_bounds__(256) void gather_kernel(
    const unsigned char* __restrict__ h8, const int* __restrict__ rowptr,
    const int* __restrict__ col, unsigned short* __restrict__ hs) {
  int n = blockIdx.x * 4 + (threadIdx.x >> 6);
  int lane = threadIdx.x & 63;
  if (n >= NN) return;
  int lo = rowptr[n], hi = rowptr[n + 1];
  const unsigned char* hl = h8 + (size_t)(lane << 3);
  u32x2 sv = *(const u32x2*)(hl + (size_t)n * 512);
  float a0[8], a1[8], tmp[8];
  dec8(sv, a0);
  #pragma unroll
  for (int i = 0; i < 8; ++i) a1[i] = 0.f;
  int j = lo;
  for (; j + 4 <= hi; j += 4) {
    int c0 = col[j], c1 = col[j + 1], c2 = col[j + 2], c3 = col[j + 3];
    u32x2 v0 = *(const u32x2*)(hl + (size_t)c0 * 512);
    u32x2 v1 = *(const u32x2*)(hl + (size_t)c1 * 512);
    u32x2 v2 = *(const u32x2*)(hl + (size_t)c2 * 512);
    u32x2 v3 = *(const u32x2*)(hl + (size_t)c3 * 512);
    dec8(v0, tmp);
    #pragma unroll
    for (int i = 0; i < 8; ++i) a0[i] += tmp[i];
    dec8(v1, tmp);
    #pragma unroll
    for (int i = 0; i < 8; ++i) a1[i] += tmp[i];
    dec8(v2, tmp);
    #pragma unroll
    for (int i = 0; i < 8; ++i) a0[i] += tmp[i];
    dec8(v3, tmp);
    #pragma unroll
    for (int i = 0; i < 8; ++i) a1[i] += tmp[i];
  }
  for (; j < hi; ++j) {
    u32x2 v0 = *(const u32x2*)(hl + (size_t)col[j] * 512);
    dec8(v0, tmp);
    #pragma unroll
    for (int i = 0; i < 8; ++i) a0[i] += tmp[i];
  }
  s16x8 o;
  #pragma unroll
  for (int i = 0; i < 8; ++i) o[i] = (short)f2bf(a0[i] + a1[i]);
  *(s16x8*)(hs + (size_t)n * HD + (lane << 3)) = o;
}

// ------- bf16 GEMM (M x 512) @ (512 x 512), BM=64 x BN=128 tiles -------
// 1252 blocks (~5/CU co-resident: cross-block overlap hides staging latency).
// LDS 24KB = A 64x64 (8KB) + B 128x64 (16KB). 4 waves, each 32x64 output.
// EPI 1: +bias, prelu, BN affine -> bf16.  EPI 2: +bias, prelu, relu -> bf16.
// EPI 4: +bias, prelu, relu -> fp8 (h table).
template <int EPI>
__global__ __launch_bounds__(256, 2) void gemm_bf16(
    const unsigned short* __restrict__ A, const unsigned short* __restrict__ Bt,
    const float* __restrict__ bias, const float* __restrict__ slope,
    const float* __restrict__ bnm, const float* __restrict__ bnv,
    const float* __restrict__ bng, const float* __restrict__ bnb,
    void* __restrict__ Cout, int M) {
  __shared__ unsigned short lds[12288];   // 24KB
  char* ldsb = (char*)lds;
  const int tid = threadIdx.x;
  const int lane = tid & 63;
  const int wid = tid >> 6;
  const int wm = wid >> 1, wn = wid & 1;

  // bijective XCD-chunked swizzle (m204)
  const unsigned bid = blockIdx.x;
  const unsigned nwg = gridDim.x;
  const unsigned q = nwg >> 3, r = nwg & 7;
  const unsigned xcd = bid & 7, idx = bid >> 3;
  const unsigned wgid = (xcd < r ? xcd * (q + 1) : r * (q + 1) + (xcd - r) * q) + idx;
  const int m0 = (int)(wgid >> 2) * 64;
  const int n0 = (int)(wgid & 3) * 128;

  f32x4 acc[2][4];
  #pragma unroll
  for (int m = 0; m < 2; ++m)
    #pragma unroll
    for (int n = 0; n < 4; ++n) acc[m][n] = (f32x4){0.f, 0.f, 0.f, 0.f};

  const int row_s = tid >> 3;   // 0..31
  const int slot_s = tid & 7;   // 0..7
  const unsigned ldso_w = (unsigned)(wid << 10);

  const unsigned swz = (unsigned)((lane & 7) << 4);
  const unsigned koff = (unsigned)((lane >> 4) << 4);
  const unsigned arow = (unsigned)((wm * 32 + (lane & 15)) * 128);
  const unsigned brow = 8192u + (unsigned)((wn * 64 + (lane & 15)) * 128);

  for (int kk = 0; kk < HD; kk += 64) {
    __syncthreads();
    // A: 64 rows x 64 k (2 rounds of 32 rows)
    #pragma unroll
    for (int i = 0; i < 2; ++i) {
      int ra = i * 32 + row_s;
      int rga = m0 + ra; rga = rga < M ? rga : M - 1;
      const unsigned short* ga = A + (size_t)rga * HD + (kk + ((slot_s ^ (ra & 7)) << 3));
      __builtin_amdgcn_global_load_lds(
          (const __attribute__((address_space(1))) unsigned int*)(const void*)ga,
          (__attribute__((address_space(3))) unsigned int*)(void*)(ldsb + (unsigned)(i * 4096) + ldso_w),
          16, 0, 0);
    }
    // B: 128 rows x 64 k (4 rounds)
    #pragma unroll
    for (int i = 0; i < 4; ++i) {
      int rb = i * 32 + row_s;
      const unsigned short* gb = Bt + (size_t)(n0 + rb) * HD + (kk + ((slot_s ^ (rb & 7)) << 3));
      __builtin_amdgcn_global_load_lds(
          (const __attribute__((address_space(1))) unsigned int*)(const void*)gb,
          (__attribute__((address_space(3))) unsigned int*)(void*)(ldsb + 8192u + (unsigned)(i * 4096) + ldso_w),
          16, 0, 0);
    }
    __syncthreads();

    #pragma unroll
    for (int s = 0; s < 2; ++s) {
      s16x8 af[2], bfr[4];
      #pragma unroll
      for (int m = 0; m < 2; ++m)
        af[m] = *(const s16x8*)(ldsb + ((arow + (unsigned)(m * 2048 + s * 64) + koff) ^ swz));
      #pragma unroll
      for (int n = 0; n < 4; ++n)
        bfr[n] = *(const s16x8*)(ldsb + ((brow + (unsigned)(n * 2048 + s * 64) + koff) ^ swz));
      #pragma unroll
      for (int m = 0; m < 2; ++m)
        #pragma unroll
        for (int n = 0; n < 4; ++n)
          acc[m][n] = __builtin_amdgcn_mfma_f32_16x16x32_bf16(af[m], bfr[n], acc[m][n], 0, 0, 0);
    }
  }

  const float al = slope[0];
  const int colb = n0 + wn * 64 + (lane & 15);
  const int rowb = m0 + wm * 32 + ((lane >> 4) << 2);
  #pragma unroll
  for (int n = 0; n < 4; ++n) {
    const int j = colb + n * 16;
    const float bi = bias[j];
    float sc = 1.f, sh = 0.f;
    if (EPI == 1) {
      sc = bng[j] * (1.f / sqrtf(bnv[j] + 1e-5f));
      sh = bnb[j] - bnm[j] * sc;
    }
    #pragma unroll
    for (int m = 0; m < 2; ++m) {
      #pragma unroll
      for (int r2 = 0; r2 < 4; ++r2) {
        int row = rowb + m * 16 + r2;
        if (row < M) {
          float v = acc[m][n][r2] + bi;
          v = v >= 0.f ? v : al * v;
          if (EPI == 1) v = v * sc + sh;
          else v = fmaxf(v, 0.f);
          if (EPI == 4)
            ((unsigned char*)Cout)[(size_t)row * HD + j] = (unsigned char)f32_to_fp8(v);
          else
            ((unsigned short*)Cout)[(size_t)row * HD + j] = f2bf(v);
        }
      }
    }
  }
}

// ---------------- FC1 GEMM: (400 x 3072) @ (3072 x 256), bf16, K-split ----
__global__ __launch_bounds__(256, 2) void fc_gemm_kernel(
    const unsigned short* __restrict__ A, const unsigned short* __restrict__ Bt,
    float* __restrict__ part) {
  __shared__ unsigned short lds[16384];
  char* ldsb = (char*)lds;
  const int tid = threadIdx.x;
  const int lane = tid & 63;
  const int wid = tid >> 6;
  const int wm = wid >> 1, wn = wid & 1;
  const int m0 = blockIdx.x * 128;
  const int n0 = blockIdx.y * 128;
  const int kbase = blockIdx.z * 512;

  f32x4 acc[4][4];
  #pragma unroll
  for (int m = 0; m < 4; ++m)
    #pragma unroll
    for (int n = 0; n < 4; ++n) acc[m][n] = (f32x4){0.f, 0.f, 0.f, 0.f};

  const int row_s = tid >> 3;
  const int slot_s = tid & 7;
  const unsigned ldso_w = (unsigned)(wid << 10);

  for (int kk = kbase; kk < kbase + 512; kk += 64) {
    __syncthreads();
    #pragma unroll
    for (int i = 0; i < 4; ++i) {
      int ra = i * 32 + row_s;
      int rga = m0 + ra; rga = rga < NG ? rga : NG - 1;
      const unsigned short* ga = A + (size_t)rga * FCK + (kk + ((slot_s ^ (ra & 7)) << 3));
      __builtin_amdgcn_global_load_lds(
          (const __attribute__((address_space(1))) unsigned int*)(const void*)ga,
          (__attribute__((address_space(3))) unsigned int*)(void*)(ldsb + (unsigned)(i * 4096) + ldso_w),
          16, 0, 0);
    }
    #pragma unroll
    for (int i = 0; i < 4; ++i) {
      int rb = i * 32 + row_s;
      const unsigned short* gb = Bt + (size_t)(n0 + rb) * FCK + (kk + ((slot_s ^ (rb & 7)) << 3));
      __builtin_amdgcn_global_load_lds(
          (const __attribute__((address_space(1))) unsigned int*)(const void*)gb,
          (__attribute__((address_space(3))) unsigned int*)(void*)(ldsb + 16384u + (unsigned)(i * 4096) + ldso_w),
          16, 0, 0);
    }
    __syncthreads();

    const unsigned swz = (unsigned)((lane & 7) << 4);
    const unsigned koff = (unsigned)((lane >> 4) << 4);
    const unsigned arow = (unsigned)((wm * 64 + (lane & 15)) * 128);
    const unsigned brow = 16384u + (unsigned)((wn * 64 + (lane & 15)) * 128);
    #pragma unroll
    for (int s = 0; s < 2; ++s) {
      s16x8 af[4], bfr[4];
      #pragma unroll
      for (int m = 0; m < 4; ++m)
        af[m] = *(const s16x8*)(ldsb + ((arow + (unsigned)(m * 2048 + s * 64) + koff) ^ swz));
      #pragma unroll
      for (int n = 0; n < 4; ++n)
        bfr[n] = *(const s16x8*)(ldsb + ((brow + (unsigned)(n * 2048 + s * 64) + koff) ^ swz));
      #pragma unroll
      for (int m = 0; m < 4; ++m)
        #pragma unroll
        for (int n = 0; n < 4; ++n)
          acc[m][n] = __builtin_amdgcn_mfma_f32_16x16x32_bf16(af[m], bfr[n], acc[m][n], 0, 0, 0);
    }
  }

  float* po = part + (size_t)blockIdx.z * (NG * FCN);
  const int colb = n0 + wn * 64 + (lane & 15);
  const int rowb = m0 + wm * 64 + ((lane >> 4) << 2);
  #pragma unroll
  for (int n = 0; n < 4; ++n) {
    const int j = colb + n * 16;
    #pragma unroll
    for (int m = 0; m < 4; ++m) {
      #pragma unroll
      for (int r = 0; r < 4; ++r) {
        int row = rowb + m * 16 + r;
        if (row < NG) po[(size_t)row * FCN + j] = acc[m][n][r];
      }
    }
  }
}

// ---------------- pooling + x_cat build (bf16, padded to 3072) ----------------
__device__ __forceinline__ int lbound(const int* __restrict__ a, int n, int v) {
  int lo = 0, hi = n;
  while (lo < hi) { int m = (lo + hi) >> 1; if (a[m] < v) lo = m + 1; else hi = m; }
  return lo;
}

__global__ __launch_bounds__(256) void pool_xcat_kernel(
    const unsigned short* __restrict__ hs, const int* __restrict__ batch,
    const float* __restrict__ stats, const float* __restrict__ adj,
    unsigned short* __restrict__ xcat) {
  int g = blockIdx.x, t = threadIdx.x;
  int lo = lbound(batch, NN, g);
  int hi = lbound(batch, NN, g + 1);
  float s0 = 0.f, s1 = 0.f;
  for (int n = lo; n < hi; ++n) {
    uint32_t v = *(const uint32_t*)(hs + (size_t)n * HD + 2 * t);
    s0 += bf2f((unsigned short)(v & 0xffffu));
    s1 += bf2f((unsigned short)(v >> 16));
  }
  unsigned short* row = xcat + (size_t)g * FCK;
  row[2 * t] = f2bf(s0);
  row[2 * t + 1] = f2bf(s1);
  if (t < 8) row[HD + t] = f2bf(stats[g * 8 + t]);
  for (int i = t; i < 2500; i += 256) row[520 + i] = f2bf(adj[(size_t)g * 2500 + i]);
  if (t < 52) row[3020 + t] = 0;
}

// ---------------- FC epilogue: bias+relu -> x_l, fc2 dot -> sigmoid ----------------
__global__ __launch_bounds__(256) void fc_epi_kernel(
    const float* __restrict__ part, const float* __restrict__ b1,
    const float* __restrict__ w2, const float* __restrict__ b2,
    float* __restrict__ outp) {
  __shared__ float red[256];
  int g = blockIdx.x, t = threadIdx.x;
  float s = b1[t];
  #pragma unroll
  for (int ks = 0; ks < 6; ++ks) s += part[(size_t)ks * (NG * FCN) + g * FCN + t];
  float xl = fmaxf(s, 0.f);
  outp[NG + g * FCN + t] = xl;
  red[t] = xl * w2[t];
  __syncthreads();
  for (int st = 128; st > 0; st >>= 1) {
    if (t < st) red[t] += red[t + st];
    __syncthreads();
  }
  if (t == 0) outp[g] = 1.f / (1.f + expf(-(red[0] + b2[0])));
}

extern "C" void kernel_launch(void* const* d_in, const int* in_sizes, int n_in,
                              void* d_out, int out_size, void* d_ws, size_t ws_size,
                              hipStream_t stream) {
  const float* x = (const float*)d_in[0];
  const int* ei = (const int*)d_in[1];
  const int* batch = (const int*)d_in[2];
  const float* stats = (const float*)d_in[3];
  const float* adj = (const float*)d_in[4];
  const float* w1 = (const float*)d_in[5];
  const float* b1 = (const float*)d_in[6];
  const float* a1 = (const float*)d_in[7];
  const float* bng = (const float*)d_in[8];
  const float* bnb = (const float*)d_in[9];
  const float* bnm = (const float*)d_in[10];
  const float* bnv = (const float*)d_in[11];
  const float* w2 = (const float*)d_in[12];
  const float* b2 = (const float*)d_in[13];
  const float* a2 = (const float*)d_in[14];
  const float* fc1w = (const float*)d_in[15];
  const float* fc1b = (const float*)d_in[16];
  const float* fc2w = (const float*)d_in[17];
  const float* fc2b = (const float*)d_in[18];
  float* outp = (float*)d_out;

  char* ws = (char*)d_ws;
  unsigned char* h8 = (unsigned char*)ws;     ws += NHID;              // fp8 h table (gather input)
  unsigned short* hsb = (unsigned short*)ws;  ws += NHID * 2;          // bf16 h+agg / final h
  unsigned short* h1b = (unsigned short*)ws;  ws += NHID * 2;          // bf16 mid
  unsigned short* w1t = (unsigned short*)ws;  ws += (size_t)3 * 512 * 512 * 2;
  unsigned short* w2t = (unsigned short*)ws;  ws += (size_t)3 * 512 * 512 * 2;
  int* deg = (int*)ws;                        ws += (size_t)NN * 4;
  int* rowptr = (int*)ws;                     ws += (size_t)(NN + 4) * 4;
  int* cursor = (int*)ws;                     ws += (size_t)NN * 4;
  int* col = (int*)ws;                        ws += (size_t)NE * 4;
  unsigned short* xcat = (unsigned short*)ws; ws += (size_t)NG * FCK * 2;
  unsigned short* fc1t = (unsigned short*)ws; ws += (size_t)FCN * FCK * 2;
  float* fcpart = (float*)ws;                 ws += (size_t)6 * NG * FCN * 4;

  // CSR build
  hipMemsetAsync(deg, 0, (size_t)NN * 4, stream);
  hist_kernel<<<(NE + 255) / 256, 256, 0, stream>>>(ei, deg);
  scan_kernel<<<1, 1024, 0, stream>>>(deg, rowptr, cursor);
  fill_kernel<<<(NE + 255) / 256, 256, 0, stream>>>(ei, cursor, col);

  cast_x_kernel<<<(int)(NHID / 1024), 256, 0, stream>>>(x, h8);
  transpose_w12_kernel<<<dim3(8, 8, 6), 256, 0, stream>>>(w1, w2, w1t, w2t);
  transpose_fc1_kernel<<<dim3(FCK / 64, FCN / 64, 1), 256, 0, stream>>>(fc1w, fc1t);

  for (int l = 0; l < 3; ++l) {
    gather_kernel<<<NN / 4, 256, 0, stream>>>(h8, rowptr, col, hsb);
    gemm_bf16<1><<<1252, 256, 0, stream>>>(hsb, w1t + (size_t)l * 262144,
        b1 + l * 512, a1 + l, bnm + l * 512, bnv + l * 512, bng + l * 512, bnb + l * 512,
        (void*)h1b, NN);
    if (l < 2) {
      gemm_bf16<4><<<1252, 256, 0, stream>>>(h1b, w2t + (size_t)l * 262144,
          b2 + l * 512, a2 + l, nullptr, nullptr, nullptr, nullptr, (void*)h8, NN);
    } else {
      gemm_bf16<2><<<1252, 256, 0, stream>>>(h1b, w2t + (size_t)l * 262144,
          b2 + l * 512, a2 + l, nullptr, nullptr, nullptr, nullptr, (void*)hsb, NN);
    }
  }

  pool_xcat_kernel<<<NG, 256, 0, stream>>>(hsb, batch, stats, adj, xcat);
  fc_gemm_kernel<<<dim3(4, 2, 6), 256, 0, stream>>>(xcat, fc1t, fcpart);
  fc_epi_kernel<<<NG, 256, 0, stream>>>(fcpart, fc1b, fc2w, fc2b, outp);
}